// Round 2
// baseline (488.544 us; speedup 1.0000x reference)
//
#include <hip/hip_runtime.h>

// Shapes fixed by the reference setup_inputs():
//   x: [B=8, F=512, T=16384] f32 ; out: [8, 16384] f32
#define TT 16384
#define BB 8
#define NB 8      // N_BANDS
#define FB 64     // F / N_BANDS

__device__ __forceinline__ float lgf(float g, float x) {
    // log1p(g*x) with g*x in [0,10): 1+g*x in [1,11) -> fast hw log is safe.
    return __logf(fmaf(g, x, 1.0f));
}

// ---------------- Kernel A: log-gamma + depthwise 5-tap diff + ReLU + freq-pool
// grid: (64 = b*8+c, 16 time tiles of 1024), block 256, 4 outputs/thread.
// Halo x_log values come from neighbor lanes via shuffle (computed once), with
// predicated scalar reloads only at wave-edge lanes.
__global__ __launch_bounds__(256) void pool_kernel(
    const float* __restrict__ x,
    const float* __restrict__ log_gamma,
    const float* __restrict__ diff_w,   // [8,1,1,5] flat
    const float* __restrict__ diff_b,   // [8]
    float* __restrict__ pool)           // [8,8,16384]
{
    const int bc   = blockIdx.x;               // b*8 + c
    const int c    = bc & 7;
    const int t    = blockIdx.y * 1024 + threadIdx.x * 4;   // this thread's t0
    const int lane = threadIdx.x & 63;
    const float* __restrict__ xb = x + (size_t)bc * FB * TT;

    const float g  = __expf(log_gamma[c]);
    const float w0 = diff_w[c * 5 + 0], w1 = diff_w[c * 5 + 1],
                w2 = diff_w[c * 5 + 2], w3 = diff_w[c * 5 + 3],
                w4 = diff_w[c * 5 + 4];
    const float bias = diff_b[c];

    float a0 = 0.f, a1 = 0.f, a2 = 0.f, a3 = 0.f;
    for (int f = 0; f < FB; ++f) {
        const float* __restrict__ row = xb + (size_t)f * TT;
        const float4 v = *reinterpret_cast<const float4*>(row + t);
        const float l2 = lgf(g, v.x), l3 = lgf(g, v.y),
                    l4 = lgf(g, v.z), l5 = lgf(g, v.w);
        // neighbor-lane x_log values; lane L-1 holds t-4..t-1 as its l2..l5,
        // lane L+1 holds t+4..t+7 as its l2..l5.
        float l0 = __shfl_up(l4, 1, 64);
        float l1 = __shfl_up(l5, 1, 64);
        float l6 = __shfl_down(l2, 1, 64);
        float l7 = __shfl_down(l3, 1, 64);
        if (lane == 0) {                 // wave edge: previous wave's data not shufflable
            l0 = (t >= 2) ? lgf(g, row[t - 2]) : 0.f;   // zero pad (SAME on x_log)
            l1 = (t >= 1) ? lgf(g, row[t - 1]) : 0.f;
        } else if (lane == 63) {
            l6 = (t + 4 < TT) ? lgf(g, row[t + 4]) : 0.f;
            l7 = (t + 5 < TT) ? lgf(g, row[t + 5]) : 0.f;
        }

        float d0 = fmaf(w0,l0, fmaf(w1,l1, fmaf(w2,l2, fmaf(w3,l3, fmaf(w4,l4, bias)))));
        float d1 = fmaf(w0,l1, fmaf(w1,l2, fmaf(w2,l3, fmaf(w3,l4, fmaf(w4,l5, bias)))));
        float d2 = fmaf(w0,l2, fmaf(w1,l3, fmaf(w2,l4, fmaf(w3,l5, fmaf(w4,l6, bias)))));
        float d3 = fmaf(w0,l3, fmaf(w1,l4, fmaf(w2,l5, fmaf(w3,l6, fmaf(w4,l7, bias)))));
        a0 += (d0 >= 0.f) ? d0 : 0.f;   // lrelu, A_LRELU = 0
        a1 += (d1 >= 0.f) ? d1 : 0.f;
        a2 += (d2 >= 0.f) ? d2 : 0.f;
        a3 += (d3 >= 0.f) ? d3 : 0.f;
    }
    *reinterpret_cast<float4*>(pool + (size_t)bc * TT + t) = make_float4(a0, a1, a2, a3);
}

// ---------------- Kernel B: (pool - avg11 - avg_b) -> band mix -> gauss15 -> ReLU
// grid: 8 batches * 16 tiles of 1024, block 256. Writes unnormalized act and a
// per-(batch,tile) max slot (every slot written -> no memset dispatch needed).
__global__ __launch_bounds__(256) void smooth_kernel(
    const float* __restrict__ pool,     // [8,8,16384]
    const float* __restrict__ avg_w,    // [8,1,11] flat
    const float* __restrict__ avg_b,    // [8]
    const float* __restrict__ mix_w,    // [1,8] flat
    const float* __restrict__ gauss_w,  // [15]
    const float* __restrict__ gauss_b,  // [1]
    float* __restrict__ out,            // [8,16384] (unnormalized act)
    float* __restrict__ pmax)           // [8*16] per-(batch,tile) maxes
{
    __shared__ float sp[NB][1024 + 24]; // pool tile, halo 12 each side (avg±5 then gauss±7)
    __shared__ float sm[1024 + 14];     // x_mix tile, halo 7 each side
    __shared__ float wmax[4];           // per-wave maxes

    const int b  = blockIdx.x >> 4;
    const int t0 = (blockIdx.x & 15) * 1024;

    for (int i = threadIdx.x; i < 1024 + 24; i += 256) {
        const int t = t0 + i - 12;
        const bool in = ((unsigned)t < (unsigned)TT);
        #pragma unroll
        for (int c = 0; c < NB; ++c)
            sp[c][i] = in ? pool[((size_t)b * NB + c) * TT + t] : 0.f;
    }
    __syncthreads();

    // x_mix[t] = sum_c mix_w[c] * (pool_c[t] - sum_j avg_w[c,j]*pool_c[t+j-5] - avg_b[c])
    for (int i = threadIdx.x; i < 1024 + 14; i += 256) {
        const int t = t0 + i - 7;
        float v = 0.f;
        if ((unsigned)t < (unsigned)TT) {     // gauss zero-pads x_mix
            #pragma unroll
            for (int c = 0; c < NB; ++c) {
                float av = 0.f;
                #pragma unroll
                for (int j = 0; j < 11; ++j)
                    av = fmaf(avg_w[c * 11 + j], sp[c][i + j], av);
                const float e = sp[c][i + 5] - av - avg_b[c];
                v = fmaf(mix_w[c], e, v);
            }
        }
        sm[i] = v;
    }
    __syncthreads();

    const float gb = gauss_b[0];
    float lmax = 0.f;
    for (int i = threadIdx.x; i < 1024; i += 256) {
        float gs = gb;
        #pragma unroll
        for (int k = 0; k < 15; ++k)
            gs = fmaf(gauss_w[k], sm[i + k], gs);
        const float a = (gs >= 0.f) ? gs : 0.f;   // lrelu, A_LRELU = 0
        out[(size_t)b * TT + t0 + i] = a;
        lmax = fmaxf(lmax, a);
    }
    #pragma unroll
    for (int off = 32; off > 0; off >>= 1)
        lmax = fmaxf(lmax, __shfl_down(lmax, off, 64));
    if ((threadIdx.x & 63) == 0) wmax[threadIdx.x >> 6] = lmax;
    __syncthreads();
    if (threadIdx.x == 0)
        pmax[blockIdx.x] = fmaxf(fmaxf(wmax[0], wmax[1]), fmaxf(wmax[2], wmax[3]));
}

// ---------------- Kernel C: reduce 16 tile-maxes per batch, divide by (max + eps)
__global__ __launch_bounds__(256) void norm_kernel(
    float* __restrict__ out, const float* __restrict__ pmax)
{
    const int i = blockIdx.x * 256 + threadIdx.x;   // grid sized exactly B*T/256
    const int b = i >> 14;                          // T = 16384; block-uniform
    const float* __restrict__ pm = pmax + b * 16;
    float m = 0.f;
    #pragma unroll
    for (int k = 0; k < 16; ++k) m = fmaxf(m, pm[k]);
    out[i] = out[i] / (m + 1e-8f);
}

extern "C" void kernel_launch(void* const* d_in, const int* in_sizes, int n_in,
                              void* d_out, int out_size, void* d_ws, size_t ws_size,
                              hipStream_t stream) {
    const float* x        = (const float*)d_in[0];
    const float* log_g    = (const float*)d_in[1];
    const float* diff_w   = (const float*)d_in[2];
    const float* diff_b   = (const float*)d_in[3];
    const float* avg_w    = (const float*)d_in[4];
    const float* avg_b    = (const float*)d_in[5];
    const float* mix_w    = (const float*)d_in[6];
    const float* gauss_w  = (const float*)d_in[7];
    const float* gauss_b  = (const float*)d_in[8];
    float* out = (float*)d_out;

    // workspace layout: pool [8*8*16384] f32 (4 MiB), then 128 floats of tile maxes
    float* pool = (float*)d_ws;
    float* pmax = (float*)((char*)d_ws + (size_t)BB * NB * TT * sizeof(float));

    pool_kernel<<<dim3(BB * NB, TT / 1024), 256, 0, stream>>>(x, log_g, diff_w, diff_b, pool);
    smooth_kernel<<<BB * (TT / 1024), 256, 0, stream>>>(pool, avg_w, avg_b, mix_w,
                                                        gauss_w, gauss_b, out, pmax);
    norm_kernel<<<(BB * TT) / 256, 256, 0, stream>>>(out, pmax);
}

// Round 3
// 394.374 us; speedup vs baseline: 1.2388x; 1.2388x over previous
//
#include <hip/hip_runtime.h>

// Shapes fixed by the reference setup_inputs():
//   x: [B=8, F=512, T=16384] f32 ; out: [8, 16384] f32
#define TT 16384
#define BB 8
#define NB 8      // N_BANDS
#define FB 64     // F / N_BANDS
#define FSPLIT 2  // freq-loop split factor (occupancy: 2048 blocks = 8192 waves = 100%)
#define FCHUNK (FB / FSPLIT)

__device__ __forceinline__ float lgf(float g, float x) {
    // log1p(g*x) with g*x in [0,10): 1+g*x in [1,11) -> fast hw log is safe.
    return __logf(fmaf(g, x, 1.0f));
}

// ---------------- Kernel A: log-gamma + depthwise 5-tap diff + ReLU + freq-pool
// grid: (64 = b*8+c, 16 time tiles, 2 freq halves), block 256, 4 outputs/thread.
// All loads unconditional from clamped addresses (no branches between loads ->
// compiler batches 3 loads/iter and unroll-4 keeps ~12 in flight per wave).
__global__ __launch_bounds__(256) void pool_kernel(
    const float* __restrict__ x,
    const float* __restrict__ log_gamma,
    const float* __restrict__ diff_w,   // [8,1,1,5] flat
    const float* __restrict__ diff_b,   // [8]
    float* __restrict__ pool_part)      // [2][64][16384]
{
    const int bc = blockIdx.x;                 // b*8 + c
    const int c  = bc & 7;
    const int t  = blockIdx.y * 1024 + threadIdx.x * 4;
    const int f0 = blockIdx.z * FCHUNK;
    const float* __restrict__ xb = x + ((size_t)bc * FB + f0) * TT;

    const float g  = __expf(log_gamma[c]);
    const float w0 = diff_w[c * 5 + 0], w1 = diff_w[c * 5 + 1],
                w2 = diff_w[c * 5 + 2], w3 = diff_w[c * 5 + 3],
                w4 = diff_w[c * 5 + 4];
    const float bias = diff_b[c];

    // loop-invariant halo masks + clamped (always-valid) halo addresses
    const bool mL = (t > 0);            // t mult of 4: t>0 => t-2,t-1 valid
    const bool mR = (t + 4 < TT);       // => t+4,t+5 both valid
    const int  tm = mL ? t - 2 : 0;     // 8B-aligned (t even)
    const int  tp = mR ? t + 4 : 0;

    float a0 = 0.f, a1 = 0.f, a2 = 0.f, a3 = 0.f;
    #pragma unroll 4
    for (int f = 0; f < FCHUNK; ++f) {
        const float* __restrict__ row = xb + (size_t)f * TT;
        const float4 v  = *reinterpret_cast<const float4*>(row + t);
        const float2 hm = *reinterpret_cast<const float2*>(row + tm);
        const float2 hp = *reinterpret_cast<const float2*>(row + tp);

        const float l2 = lgf(g, v.x), l3 = lgf(g, v.y),
                    l4 = lgf(g, v.z), l5 = lgf(g, v.w);
        const float l0 = mL ? lgf(g, hm.x) : 0.f;   // zero pad (SAME on x_log)
        const float l1 = mL ? lgf(g, hm.y) : 0.f;
        const float l6 = mR ? lgf(g, hp.x) : 0.f;
        const float l7 = mR ? lgf(g, hp.y) : 0.f;

        float d0 = fmaf(w0,l0, fmaf(w1,l1, fmaf(w2,l2, fmaf(w3,l3, fmaf(w4,l4, bias)))));
        float d1 = fmaf(w0,l1, fmaf(w1,l2, fmaf(w2,l3, fmaf(w3,l4, fmaf(w4,l5, bias)))));
        float d2 = fmaf(w0,l2, fmaf(w1,l3, fmaf(w2,l4, fmaf(w3,l5, fmaf(w4,l6, bias)))));
        float d3 = fmaf(w0,l3, fmaf(w1,l4, fmaf(w2,l5, fmaf(w3,l6, fmaf(w4,l7, bias)))));
        a0 += (d0 >= 0.f) ? d0 : 0.f;   // lrelu, A_LRELU = 0
        a1 += (d1 >= 0.f) ? d1 : 0.f;
        a2 += (d2 >= 0.f) ? d2 : 0.f;
        a3 += (d3 >= 0.f) ? d3 : 0.f;
    }
    float* __restrict__ po = pool_part + ((size_t)blockIdx.z * (BB * NB) + bc) * TT;
    *reinterpret_cast<float4*>(po + t) = make_float4(a0, a1, a2, a3);
}

// ---------------- Kernel B: sum partials -> (pool - avg11 - avg_b) -> mix -> gauss15 -> ReLU
// grid: 8 batches * 16 tiles of 1024, block 256. Writes unnormalized act and a
// per-(batch,tile) max slot (every slot written -> no memset dispatch needed).
__global__ __launch_bounds__(256) void smooth_kernel(
    const float* __restrict__ pool_part, // [2][64][16384]
    const float* __restrict__ avg_w,    // [8,1,11] flat
    const float* __restrict__ avg_b,    // [8]
    const float* __restrict__ mix_w,    // [1,8] flat
    const float* __restrict__ gauss_w,  // [15]
    const float* __restrict__ gauss_b,  // [1]
    float* __restrict__ out,            // [8,16384] (unnormalized act)
    float* __restrict__ pmax)           // [8*16] per-(batch,tile) maxes
{
    __shared__ float sp[NB][1024 + 24]; // pool tile, halo 12 each side (avg±5 then gauss±7)
    __shared__ float sm[1024 + 14];     // x_mix tile, halo 7 each side
    __shared__ float wmax[4];           // per-wave maxes

    const int b  = blockIdx.x >> 4;
    const int t0 = (blockIdx.x & 15) * 1024;

    for (int i = threadIdx.x; i < 1024 + 24; i += 256) {
        const int t = t0 + i - 12;
        const bool in = ((unsigned)t < (unsigned)TT);
        #pragma unroll
        for (int c = 0; c < NB; ++c) {
            const size_t off = ((size_t)b * NB + c) * TT + t;
            sp[c][i] = in ? (pool_part[off] + pool_part[(size_t)(BB * NB) * TT + off]) : 0.f;
        }
    }
    __syncthreads();

    // x_mix[t] = sum_c mix_w[c] * (pool_c[t] - sum_j avg_w[c,j]*pool_c[t+j-5] - avg_b[c])
    for (int i = threadIdx.x; i < 1024 + 14; i += 256) {
        const int t = t0 + i - 7;
        float v = 0.f;
        if ((unsigned)t < (unsigned)TT) {     // gauss zero-pads x_mix
            #pragma unroll
            for (int c = 0; c < NB; ++c) {
                float av = 0.f;
                #pragma unroll
                for (int j = 0; j < 11; ++j)
                    av = fmaf(avg_w[c * 11 + j], sp[c][i + j], av);
                const float e = sp[c][i + 5] - av - avg_b[c];
                v = fmaf(mix_w[c], e, v);
            }
        }
        sm[i] = v;
    }
    __syncthreads();

    const float gb = gauss_b[0];
    float lmax = 0.f;
    for (int i = threadIdx.x; i < 1024; i += 256) {
        float gs = gb;
        #pragma unroll
        for (int k = 0; k < 15; ++k)
            gs = fmaf(gauss_w[k], sm[i + k], gs);
        const float a = (gs >= 0.f) ? gs : 0.f;   // lrelu, A_LRELU = 0
        out[(size_t)b * TT + t0 + i] = a;
        lmax = fmaxf(lmax, a);
    }
    #pragma unroll
    for (int off = 32; off > 0; off >>= 1)
        lmax = fmaxf(lmax, __shfl_down(lmax, off, 64));
    if ((threadIdx.x & 63) == 0) wmax[threadIdx.x >> 6] = lmax;
    __syncthreads();
    if (threadIdx.x == 0)
        pmax[blockIdx.x] = fmaxf(fmaxf(wmax[0], wmax[1]), fmaxf(wmax[2], wmax[3]));
}

// ---------------- Kernel C: reduce 16 tile-maxes per batch, divide by (max + eps)
__global__ __launch_bounds__(256) void norm_kernel(
    float* __restrict__ out, const float* __restrict__ pmax)
{
    const int i = blockIdx.x * 256 + threadIdx.x;   // grid sized exactly B*T/256
    const int b = i >> 14;                          // T = 16384; block-uniform
    const float* __restrict__ pm = pmax + b * 16;
    float m = 0.f;
    #pragma unroll
    for (int k = 0; k < 16; ++k) m = fmaxf(m, pm[k]);
    out[i] = out[i] / (m + 1e-8f);
}

extern "C" void kernel_launch(void* const* d_in, const int* in_sizes, int n_in,
                              void* d_out, int out_size, void* d_ws, size_t ws_size,
                              hipStream_t stream) {
    const float* x        = (const float*)d_in[0];
    const float* log_g    = (const float*)d_in[1];
    const float* diff_w   = (const float*)d_in[2];
    const float* diff_b   = (const float*)d_in[3];
    const float* avg_w    = (const float*)d_in[4];
    const float* avg_b    = (const float*)d_in[5];
    const float* mix_w    = (const float*)d_in[6];
    const float* gauss_w  = (const float*)d_in[7];
    const float* gauss_b  = (const float*)d_in[8];
    float* out = (float*)d_out;

    // workspace: pool_part [2][64][16384] f32 (8 MiB), then 128 floats of tile maxes
    float* pool_part = (float*)d_ws;
    float* pmax = (float*)((char*)d_ws + (size_t)FSPLIT * BB * NB * TT * sizeof(float));

    pool_kernel<<<dim3(BB * NB, TT / 1024, FSPLIT), 256, 0, stream>>>(
        x, log_g, diff_w, diff_b, pool_part);
    smooth_kernel<<<BB * (TT / 1024), 256, 0, stream>>>(pool_part, avg_w, avg_b, mix_w,
                                                        gauss_w, gauss_b, out, pmax);
    norm_kernel<<<(BB * TT) / 256, 256, 0, stream>>>(out, pmax);
}

// Round 8
// 385.325 us; speedup vs baseline: 1.2679x; 1.0235x over previous
//
#include <hip/hip_runtime.h>

// Shapes fixed by the reference setup_inputs():
//   x: [B=8, F=512, T=16384] f32 ; out: [8, 16384] f32
#define TT 16384
#define BB 8
#define NB 8       // N_BANDS
#define FB 64      // F / N_BANDS
#define TILE 2048  // time elements per block (256 thr * 8)
#define FSPLIT 4   // freq-loop split (grid = 64*8*4 = 2048 blocks = 100% residency)
#define FCHUNK (FB / FSPLIT)

__device__ __forceinline__ float lgf(float g, float x) {
    // log1p(g*x) with g*x in [0,10): 1+g*x in [1,11) -> fast hw log is safe.
    return __logf(fmaf(g, x, 1.0f));
}

// ---------------- Kernel A: log-gamma + depthwise 5-tap diff + ReLU + freq-pool
// 8 outputs/thread; per freq-row: 2 float4 + 2 float2 clamped loads, register
// double-buffered (next row's loads issued BEFORE current row's compute, so
// each wave always has 4 loads in flight -> latency hidden at 8 waves/SIMD).
__global__ __launch_bounds__(256) void pool_kernel(
    const float* __restrict__ x,
    const float* __restrict__ log_gamma,
    const float* __restrict__ diff_w,   // [8,1,1,5] flat
    const float* __restrict__ diff_b,   // [8]
    float* __restrict__ pool_part)      // [FSPLIT][64][16384]
{
    const int bc = blockIdx.x;                 // b*8 + c
    const int c  = bc & 7;
    const int t0 = blockIdx.y * TILE + threadIdx.x * 8;
    const int f0 = blockIdx.z * FCHUNK;
    const float* __restrict__ xb = x + ((size_t)bc * FB + f0) * TT;

    const float g  = __expf(log_gamma[c]);
    const float w0 = diff_w[c * 5 + 0], w1 = diff_w[c * 5 + 1],
                w2 = diff_w[c * 5 + 2], w3 = diff_w[c * 5 + 3],
                w4 = diff_w[c * 5 + 4];
    const float bias = diff_b[c];

    // loop-invariant halo masks + clamped (always-valid, aligned) halo addresses
    const bool mL = (t0 > 0);             // t0 mult of 8 -> t0-2,t0-1 valid iff t0>0
    const bool mR = (t0 + 10 <= TT);      // t0+8,t0+9 both in range
    const int  tm = mL ? t0 - 2 : 0;      // 8B-aligned (t0 even)
    const int  tp = mR ? t0 + 8 : 0;

    float acc[8] = {0.f,0.f,0.f,0.f,0.f,0.f,0.f,0.f};

    // prime the pipeline: row 0 loads
    float4 va = *reinterpret_cast<const float4*>(xb + t0);
    float4 vb = *reinterpret_cast<const float4*>(xb + t0 + 4);
    float2 ha = *reinterpret_cast<const float2*>(xb + tm);
    float2 hb = *reinterpret_cast<const float2*>(xb + tp);

    for (int f = 0; f < FCHUNK; ++f) {
        // issue next row's loads first (clamped to last row to stay in-bounds)
        const int fn = (f + 1 < FCHUNK) ? f + 1 : f;
        const float* __restrict__ nrow = xb + (size_t)fn * TT;
        const float4 nva = *reinterpret_cast<const float4*>(nrow + t0);
        const float4 nvb = *reinterpret_cast<const float4*>(nrow + t0 + 4);
        const float2 nha = *reinterpret_cast<const float2*>(nrow + tm);
        const float2 nhb = *reinterpret_cast<const float2*>(nrow + tp);

        // x_log window t0-2 .. t0+9 (zero outside [0,T): SAME padding on x_log)
        float L[12];
        L[0]  = mL ? lgf(g, ha.x) : 0.f;
        L[1]  = mL ? lgf(g, ha.y) : 0.f;
        L[2]  = lgf(g, va.x); L[3] = lgf(g, va.y);
        L[4]  = lgf(g, va.z); L[5] = lgf(g, va.w);
        L[6]  = lgf(g, vb.x); L[7] = lgf(g, vb.y);
        L[8]  = lgf(g, vb.z); L[9] = lgf(g, vb.w);
        L[10] = mR ? lgf(g, hb.x) : 0.f;
        L[11] = mR ? lgf(g, hb.y) : 0.f;

        #pragma unroll
        for (int j = 0; j < 8; ++j) {
            float d = fmaf(w0, L[j],
                      fmaf(w1, L[j+1],
                      fmaf(w2, L[j+2],
                      fmaf(w3, L[j+3],
                      fmaf(w4, L[j+4], bias)))));
            acc[j] += (d >= 0.f) ? d : 0.f;   // lrelu, A_LRELU = 0
        }
        va = nva; vb = nvb; ha = nha; hb = nhb;
    }

    float* __restrict__ po = pool_part + ((size_t)blockIdx.z * (BB * NB) + bc) * TT + t0;
    *reinterpret_cast<float4*>(po)     = make_float4(acc[0], acc[1], acc[2], acc[3]);
    *reinterpret_cast<float4*>(po + 4) = make_float4(acc[4], acc[5], acc[6], acc[7]);
}

// ---------------- Kernel B: sum partials -> (pool - avg11 - avg_b) -> mix -> gauss15 -> ReLU
// grid: 8 batches * 16 tiles of 1024, block 256. Writes unnormalized act and a
// per-(batch,tile) max slot (every slot written -> no memset dispatch needed).
__global__ __launch_bounds__(256) void smooth_kernel(
    const float* __restrict__ pool_part, // [FSPLIT][64][16384]
    const float* __restrict__ avg_w,    // [8,1,11] flat
    const float* __restrict__ avg_b,    // [8]
    const float* __restrict__ mix_w,    // [1,8] flat
    const float* __restrict__ gauss_w,  // [15]
    const float* __restrict__ gauss_b,  // [1]
    float* __restrict__ out,            // [8,16384] (unnormalized act)
    float* __restrict__ pmax)           // [8*16] per-(batch,tile) maxes
{
    __shared__ float sp[NB][1024 + 24]; // pool tile, halo 12 each side (avg±5 then gauss±7)
    __shared__ float sm[1024 + 14];     // x_mix tile, halo 7 each side
    __shared__ float wmax[4];           // per-wave maxes

    const int b  = blockIdx.x >> 4;
    const int t0 = (blockIdx.x & 15) * 1024;

    for (int i = threadIdx.x; i < 1024 + 24; i += 256) {
        const int t = t0 + i - 12;
        const bool in = ((unsigned)t < (unsigned)TT);
        const int tc = in ? t : (t < 0 ? 0 : TT - 1);   // clamped: address always valid
        #pragma unroll
        for (int c = 0; c < NB; ++c) {
            const size_t off = ((size_t)b * NB + c) * TT + tc;
            float s = 0.f;
            #pragma unroll
            for (int z = 0; z < FSPLIT; ++z)
                s += pool_part[(size_t)z * (BB * NB) * TT + off];
            sp[c][i] = in ? s : 0.f;    // zero-pad semantics preserved
        }
    }
    __syncthreads();

    // x_mix[t] = sum_c mix_w[c] * (pool_c[t] - sum_j avg_w[c,j]*pool_c[t+j-5] - avg_b[c])
    for (int i = threadIdx.x; i < 1024 + 14; i += 256) {
        const int t = t0 + i - 7;
        float v = 0.f;
        if ((unsigned)t < (unsigned)TT) {     // gauss zero-pads x_mix
            #pragma unroll
            for (int c = 0; c < NB; ++c) {
                float av = 0.f;
                #pragma unroll
                for (int j = 0; j < 11; ++j)
                    av = fmaf(avg_w[c * 11 + j], sp[c][i + j], av);
                const float e = sp[c][i + 5] - av - avg_b[c];
                v = fmaf(mix_w[c], e, v);
            }
        }
        sm[i] = v;
    }
    __syncthreads();

    const float gb = gauss_b[0];
    float lmax = 0.f;
    for (int i = threadIdx.x; i < 1024; i += 256) {
        float gs = gb;
        #pragma unroll
        for (int k = 0; k < 15; ++k)
            gs = fmaf(gauss_w[k], sm[i + k], gs);
        const float a = (gs >= 0.f) ? gs : 0.f;   // lrelu, A_LRELU = 0
        out[(size_t)b * TT + t0 + i] = a;
        lmax = fmaxf(lmax, a);
    }
    #pragma unroll
    for (int off = 32; off > 0; off >>= 1)
        lmax = fmaxf(lmax, __shfl_down(lmax, off, 64));
    if ((threadIdx.x & 63) == 0) wmax[threadIdx.x >> 6] = lmax;
    __syncthreads();
    if (threadIdx.x == 0)
        pmax[blockIdx.x] = fmaxf(fmaxf(wmax[0], wmax[1]), fmaxf(wmax[2], wmax[3]));
}

// ---------------- Kernel C: reduce 16 tile-maxes per batch, divide by (max + eps)
__global__ __launch_bounds__(256) void norm_kernel(
    float* __restrict__ out, const float* __restrict__ pmax)
{
    const int i = blockIdx.x * 256 + threadIdx.x;   // grid sized exactly B*T/256
    const int b = i >> 14;                          // T = 16384; block-uniform
    const float* __restrict__ pm = pmax + b * 16;
    float m = 0.f;
    #pragma unroll
    for (int k = 0; k < 16; ++k) m = fmaxf(m, pm[k]);
    out[i] = out[i] / (m + 1e-8f);
}

extern "C" void kernel_launch(void* const* d_in, const int* in_sizes, int n_in,
                              void* d_out, int out_size, void* d_ws, size_t ws_size,
                              hipStream_t stream) {
    const float* x        = (const float*)d_in[0];
    const float* log_g    = (const float*)d_in[1];
    const float* diff_w   = (const float*)d_in[2];
    const float* diff_b   = (const float*)d_in[3];
    const float* avg_w    = (const float*)d_in[4];
    const float* avg_b    = (const float*)d_in[5];
    const float* mix_w    = (const float*)d_in[6];
    const float* gauss_w  = (const float*)d_in[7];
    const float* gauss_b  = (const float*)d_in[8];
    float* out = (float*)d_out;

    // workspace: pool_part [4][64][16384] f32 (16 MiB), then 128 floats of tile maxes
    float* pool_part = (float*)d_ws;
    float* pmax = (float*)((char*)d_ws + (size_t)FSPLIT * BB * NB * TT * sizeof(float));

    pool_kernel<<<dim3(BB * NB, TT / TILE, FSPLIT), 256, 0, stream>>>(
        x, log_g, diff_w, diff_b, pool_part);
    smooth_kernel<<<BB * (TT / 1024), 256, 0, stream>>>(pool_part, avg_w, avg_b, mix_w,
                                                        gauss_w, gauss_b, out, pmax);
    norm_kernel<<<(BB * TT) / 256, 256, 0, stream>>>(out, pmax);
}

// Round 10
// 385.062 us; speedup vs baseline: 1.2687x; 1.0007x over previous
//
#include <hip/hip_runtime.h>

// Shapes fixed by the reference setup_inputs():
//   x: [B=8, F=512, T=16384] f32 ; out: [8, 16384] f32
#define TT 16384
#define BB 8
#define NB 8       // N_BANDS
#define FB 64      // F / N_BANDS
#define TILE 2048  // t-span per block (4 waves * 512)
#define WTS 512    // t-span per wave
#define FSPLIT 4   // freq-loop split (grid = 64*8*4 = 2048 blocks = max residency)
#define FCHUNK (FB / FSPLIT)
#define LDSW 520   // floats per wave LDS region: 4 pad | 512 | 4 pad

__device__ __forceinline__ float lgf(float g, float x) {
    // log1p(g*x) with g*x in [0,10): 1+g*x in [1,11) -> fast hw log is safe.
    // lgf(g,0) = __logf(1) = 0 -> zero-padding of x_log falls out automatically.
    return __logf(fmaf(g, x, 1.0f));
}

// ---------------- Kernel A: log-gamma + depthwise 5-tap diff + ReLU + freq-pool
// Each wave owns a contiguous 512-float t-span. Per freq row:
//   2 perfectly-coalesced float4 loads (lane i -> consecutive 16B)
//   -> logs in-register (elementwise, position-agnostic)
//   -> stage to wave-private LDS (4|512|4 with halo pads; same-wave DS ops are
//      in-order, so no barriers and no double buffer needed)
//   -> each thread ds_read_b128 x4 its aligned 16-float window, 5-tap conv,
//      ReLU, accumulate. Next row's global loads issued before the LDS reads.
__global__ __launch_bounds__(256) void pool_kernel(
    const float* __restrict__ x,
    const float* __restrict__ log_gamma,
    const float* __restrict__ diff_w,   // [8,1,1,5] flat
    const float* __restrict__ diff_b,   // [8]
    float* __restrict__ pool_part)      // [FSPLIT][64][16384]
{
    __shared__ float lds[4 * LDSW];

    const int bc = blockIdx.x;                 // b*8 + c
    const int c  = bc & 7;
    const int w  = threadIdx.x >> 6;           // wave id in block
    const int l  = threadIdx.x & 63;           // lane
    const int W  = blockIdx.y * TILE + w * WTS; // wave t-base
    const int f0 = blockIdx.z * FCHUNK;
    const float* __restrict__ xb = x + ((size_t)bc * FB + f0) * TT;

    const float g  = __expf(log_gamma[c]);
    const float w0 = diff_w[c * 5 + 0], w1 = diff_w[c * 5 + 1],
                w2 = diff_w[c * 5 + 2], w3 = diff_w[c * 5 + 3],
                w4 = diff_w[c * 5 + 4];
    const float bias = diff_b[c];

    float* __restrict__ Lb = &lds[w * LDSW];   // wave-private LDS region

    // halo duty: lanes 0..3 -> left pad (t = W-4+l), lanes 4..7 -> right pad
    int hidx = 0, lidx = 0;
    if (l < 4)      { hidx = W - 4 + l;        lidx = l; }
    else if (l < 8) { hidx = W + WTS + (l - 4); lidx = 4 + WTS + (l - 4); }
    const bool hin   = (l < 8) && (hidx >= 0) && (hidx < TT);
    const int  hsafe = hin ? hidx : 0;

    float acc[8] = {0.f,0.f,0.f,0.f,0.f,0.f,0.f,0.f};

    // prime: row 0 loads (coalesced main pair + tiny halo)
    float4 ga = *reinterpret_cast<const float4*>(xb + W + l * 4);
    float4 gb = *reinterpret_cast<const float4*>(xb + W + 256 + l * 4);
    float  gh = hin ? xb[hsafe] : 0.f;

    for (int f = 0; f < FCHUNK; ++f) {
        // logs of current row (elementwise; lane position irrelevant)
        const float lg0 = lgf(g, ga.x), lg1 = lgf(g, ga.y),
                    lg2 = lgf(g, ga.z), lg3 = lgf(g, ga.w);
        const float lg4 = lgf(g, gb.x), lg5 = lgf(g, gb.y),
                    lg6 = lgf(g, gb.z), lg7 = lgf(g, gb.w);
        const float lgh = lgf(g, gh);          // 0 for out-of-range (gh=0)

        // stage to LDS (contiguous b128 writes: conflict-free)
        *reinterpret_cast<float4*>(Lb + 4 + l * 4)       = make_float4(lg0, lg1, lg2, lg3);
        *reinterpret_cast<float4*>(Lb + 4 + 256 + l * 4) = make_float4(lg4, lg5, lg6, lg7);
        if (l < 8) Lb[lidx] = lgh;

        // prefetch next row's globals (clamped to last row; stays in-bounds)
        const int fn = (f + 1 < FCHUNK) ? f + 1 : f;
        const float* __restrict__ nrow = xb + (size_t)fn * TT;
        const float4 nga = *reinterpret_cast<const float4*>(nrow + W + l * 4);
        const float4 ngb = *reinterpret_cast<const float4*>(nrow + W + 256 + l * 4);
        const float  ngh = hin ? nrow[hsafe] : 0.f;

        // read this thread's aligned 16-float window [t0-4 .. t0+12), t0 = l*8
        const float* __restrict__ Lp = Lb + 4 + l * 8;
        const float4 r0 = *reinterpret_cast<const float4*>(Lp - 4);
        const float4 r1 = *reinterpret_cast<const float4*>(Lp);
        const float4 r2 = *reinterpret_cast<const float4*>(Lp + 4);
        const float4 r3 = *reinterpret_cast<const float4*>(Lp + 8);
        // L[k] = x_log at t0-2+k, k = 0..11
        const float L[12] = {r0.z, r0.w, r1.x, r1.y, r1.z, r1.w,
                             r2.x, r2.y, r2.z, r2.w, r3.x, r3.y};

        #pragma unroll
        for (int j = 0; j < 8; ++j) {
            const float d = fmaf(w0, L[j],
                            fmaf(w1, L[j + 1],
                            fmaf(w2, L[j + 2],
                            fmaf(w3, L[j + 3],
                            fmaf(w4, L[j + 4], bias)))));
            acc[j] += (d >= 0.f) ? d : 0.f;    // lrelu, A_LRELU = 0
        }
        ga = nga; gb = ngb; gh = ngh;
    }

    float* __restrict__ po = pool_part + ((size_t)blockIdx.z * (BB * NB) + bc) * TT
                             + W + l * 8;
    *reinterpret_cast<float4*>(po)     = make_float4(acc[0], acc[1], acc[2], acc[3]);
    *reinterpret_cast<float4*>(po + 4) = make_float4(acc[4], acc[5], acc[6], acc[7]);
}

// ---------------- Kernel B: sum partials -> (pool - avg11 - avg_b) -> mix -> gauss15 -> ReLU
// grid: 8 batches * 16 tiles of 1024, block 256. Writes unnormalized act and a
// per-(batch,tile) max slot (every slot written -> no memset dispatch needed).
__global__ __launch_bounds__(256) void smooth_kernel(
    const float* __restrict__ pool_part, // [FSPLIT][64][16384]
    const float* __restrict__ avg_w,    // [8,1,11] flat
    const float* __restrict__ avg_b,    // [8]
    const float* __restrict__ mix_w,    // [1,8] flat
    const float* __restrict__ gauss_w,  // [15]
    const float* __restrict__ gauss_b,  // [1]
    float* __restrict__ out,            // [8,16384] (unnormalized act)
    float* __restrict__ pmax)           // [8*16] per-(batch,tile) maxes
{
    __shared__ float sp[NB][1024 + 24]; // pool tile, halo 12 each side (avg±5 then gauss±7)
    __shared__ float sm[1024 + 14];     // x_mix tile, halo 7 each side
    __shared__ float wmax[4];           // per-wave maxes

    const int b  = blockIdx.x >> 4;
    const int t0 = (blockIdx.x & 15) * 1024;

    for (int i = threadIdx.x; i < 1024 + 24; i += 256) {
        const int t = t0 + i - 12;
        const bool in = ((unsigned)t < (unsigned)TT);
        const int tc = in ? t : (t < 0 ? 0 : TT - 1);   // clamped: address always valid
        #pragma unroll
        for (int c = 0; c < NB; ++c) {
            const size_t off = ((size_t)b * NB + c) * TT + tc;
            float s = 0.f;
            #pragma unroll
            for (int z = 0; z < FSPLIT; ++z)
                s += pool_part[(size_t)z * (BB * NB) * TT + off];
            sp[c][i] = in ? s : 0.f;    // zero-pad semantics preserved
        }
    }
    __syncthreads();

    // x_mix[t] = sum_c mix_w[c] * (pool_c[t] - sum_j avg_w[c,j]*pool_c[t+j-5] - avg_b[c])
    for (int i = threadIdx.x; i < 1024 + 14; i += 256) {
        const int t = t0 + i - 7;
        float v = 0.f;
        if ((unsigned)t < (unsigned)TT) {     // gauss zero-pads x_mix
            #pragma unroll
            for (int c = 0; c < NB; ++c) {
                float av = 0.f;
                #pragma unroll
                for (int j = 0; j < 11; ++j)
                    av = fmaf(avg_w[c * 11 + j], sp[c][i + j], av);
                const float e = sp[c][i + 5] - av - avg_b[c];
                v = fmaf(mix_w[c], e, v);
            }
        }
        sm[i] = v;
    }
    __syncthreads();

    const float gb = gauss_b[0];
    float lmax = 0.f;
    for (int i = threadIdx.x; i < 1024; i += 256) {
        float gs = gb;
        #pragma unroll
        for (int k = 0; k < 15; ++k)
            gs = fmaf(gauss_w[k], sm[i + k], gs);
        const float a = (gs >= 0.f) ? gs : 0.f;   // lrelu, A_LRELU = 0
        out[(size_t)b * TT + t0 + i] = a;
        lmax = fmaxf(lmax, a);
    }
    #pragma unroll
    for (int off = 32; off > 0; off >>= 1)
        lmax = fmaxf(lmax, __shfl_down(lmax, off, 64));
    if ((threadIdx.x & 63) == 0) wmax[threadIdx.x >> 6] = lmax;
    __syncthreads();
    if (threadIdx.x == 0)
        pmax[blockIdx.x] = fmaxf(fmaxf(wmax[0], wmax[1]), fmaxf(wmax[2], wmax[3]));
}

// ---------------- Kernel C: reduce 16 tile-maxes per batch, divide by (max + eps)
__global__ __launch_bounds__(256) void norm_kernel(
    float* __restrict__ out, const float* __restrict__ pmax)
{
    const int i = blockIdx.x * 256 + threadIdx.x;   // grid sized exactly B*T/256
    const int b = i >> 14;                          // T = 16384; block-uniform
    const float* __restrict__ pm = pmax + b * 16;
    float m = 0.f;
    #pragma unroll
    for (int k = 0; k < 16; ++k) m = fmaxf(m, pm[k]);
    out[i] = out[i] / (m + 1e-8f);
}

extern "C" void kernel_launch(void* const* d_in, const int* in_sizes, int n_in,
                              void* d_out, int out_size, void* d_ws, size_t ws_size,
                              hipStream_t stream) {
    const float* x        = (const float*)d_in[0];
    const float* log_g    = (const float*)d_in[1];
    const float* diff_w   = (const float*)d_in[2];
    const float* diff_b   = (const float*)d_in[3];
    const float* avg_w    = (const float*)d_in[4];
    const float* avg_b    = (const float*)d_in[5];
    const float* mix_w    = (const float*)d_in[6];
    const float* gauss_w  = (const float*)d_in[7];
    const float* gauss_b  = (const float*)d_in[8];
    float* out = (float*)d_out;

    // workspace: pool_part [4][64][16384] f32 (16 MiB), then 128 floats of tile maxes
    float* pool_part = (float*)d_ws;
    float* pmax = (float*)((char*)d_ws + (size_t)FSPLIT * BB * NB * TT * sizeof(float));

    pool_kernel<<<dim3(BB * NB, TT / TILE, FSPLIT), 256, 0, stream>>>(
        x, log_g, diff_w, diff_b, pool_part);
    smooth_kernel<<<BB * (TT / 1024), 256, 0, stream>>>(pool_part, avg_w, avg_b, mix_w,
                                                        gauss_w, gauss_b, out, pmax);
    norm_kernel<<<(BB * TT) / 256, 256, 0, stream>>>(out, pmax);
}